// Round 2
// baseline (537.534 us; speedup 1.0000x reference)
//
#include <hip/hip_runtime.h>

constexpr int kB = 8, kN = 8192, kS = 2048;
constexpr int kD1 = 128, kD2 = 256, kCin = 384, kM0 = 256, kM1 = 128;
constexpr float kEps = 1e-5f;

typedef float f32x4 __attribute__((ext_vector_type(4)));

// ---------------- Kernel 1: 3-NN + inverse-distance interpolation ----------
// Two-pass top-3:
//   pass 1: fp32 scan for the 3rd-smallest "reduced distance" d' = |s|^2-2p.s
//           (|p|^2 dropped: constant per query, order-preserving) using two
//           independent branchless min/med3 chains (3 VALU ops per insert).
//   pass 2: fp32 rescan; only d' <= m2+1e-3 (fp32 err <= ~2.4e-5, margin 40x)
//           takes the exact fp64 (p-s)^2 insert with index, strict '<' so ties
//           keep the lowest index (matches lax.top_k / np argsort order).
__global__ __launch_bounds__(256) void knn_interp_kernel(
    const float* __restrict__ xyz1, const float* __restrict__ xyz2,
    const float* __restrict__ points2, float* __restrict__ interp)
{
    __shared__ f32x4 sp[kS];                 // (sx, sy, sz, |s|^2)  32 KB
    const int b = blockIdx.x >> 5;           // 32 blocks per batch
    const int n0 = (blockIdx.x & 31) << 8;   // 256 points per block
    const int t = threadIdx.x;
    const float* x2 = xyz2 + b * 3 * kS;
    for (int s = t; s < kS; s += 256) {
        float sx = x2[s], sy = x2[kS + s], sz = x2[2 * kS + s];
        f32x4 q = {sx, sy, sz, fmaf(sx, sx, fmaf(sy, sy, sz * sz))};
        sp[s] = q;
    }
    __syncthreads();
    const int n = n0 + t;
    const float* x1 = xyz1 + b * 3 * kN;
    const float px = x1[n], py = x1[kN + n], pz = x1[2 * kN + n];
    const float ax = -2.f * px, ay = -2.f * py, az = -2.f * pz;

    // ---- pass 1: 3rd-smallest fp32 d', two chains (even/odd), no indices
    float a0 = 1e30f, a1 = 1e30f, a2 = 1e30f;
    float c0 = 1e30f, c1 = 1e30f, c2 = 1e30f;
#pragma unroll 2
    for (int s = 0; s < kS; s += 4) {
        f32x4 q0 = sp[s], q1 = sp[s + 1], q2 = sp[s + 2], q3 = sp[s + 3];
        float e0 = fmaf(ax, q0[0], fmaf(ay, q0[1], fmaf(az, q0[2], q0[3])));
        float e1 = fmaf(ax, q1[0], fmaf(ay, q1[1], fmaf(az, q1[2], q1[3])));
        float e2 = fmaf(ax, q2[0], fmaf(ay, q2[1], fmaf(az, q2[2], q2[3])));
        float e3 = fmaf(ax, q3[0], fmaf(ay, q3[1], fmaf(az, q3[2], q3[3])));
        float t1, t2;
        t1 = __builtin_amdgcn_fmed3f(e0, a0, a1);
        t2 = __builtin_amdgcn_fmed3f(e0, a1, a2);
        a0 = fminf(a0, e0); a1 = t1; a2 = t2;
        t1 = __builtin_amdgcn_fmed3f(e1, c0, c1);
        t2 = __builtin_amdgcn_fmed3f(e1, c1, c2);
        c0 = fminf(c0, e1); c1 = t1; c2 = t2;
        t1 = __builtin_amdgcn_fmed3f(e2, a0, a1);
        t2 = __builtin_amdgcn_fmed3f(e2, a1, a2);
        a0 = fminf(a0, e2); a1 = t1; a2 = t2;
        t1 = __builtin_amdgcn_fmed3f(e3, c0, c1);
        t2 = __builtin_amdgcn_fmed3f(e3, c1, c2);
        c0 = fminf(c0, e3); c1 = t1; c2 = t2;
    }
    // 3rd smallest of the merged 6 sorted values
    const float m2 = fminf(fminf(fmaxf(a1, c0), fmaxf(a0, c1)), fminf(a2, c2));
    const float cutoff = m2 + 1e-3f;

    // ---- pass 2: exact fp64 top-3 (with indices) among filtered candidates
    double d0 = 1e300, d1 = 1e300, d2 = 1e300;
    int i0 = 0, i1 = 0, i2 = 0;
    const double dpx = (double)px, dpy = (double)py, dpz = (double)pz;
    for (int s = 0; s < kS; ++s) {
        f32x4 q = sp[s];
        float df = fmaf(ax, q[0], fmaf(ay, q[1], fmaf(az, q[2], q[3])));
        if (df <= cutoff) {
            double ex = dpx - (double)q[0], ey = dpy - (double)q[1], ez = dpz - (double)q[2];
            double d = ex * ex + ey * ey + ez * ez;
            if (d < d2) {
                if (d < d1) {
                    if (d < d0) { d2 = d1; i2 = i1; d1 = d0; i1 = i0; d0 = d; i0 = s; }
                    else        { d2 = d1; i2 = i1; d1 = d;  i1 = s; }
                } else          { d2 = d;  i2 = s; }
            }
        }
    }
    const double r0 = 1.0 / (d0 + 1e-8), r1 = 1.0 / (d1 + 1e-8), r2 = 1.0 / (d2 + 1e-8);
    const double rs = 1.0 / (r0 + r1 + r2);
    const float w0 = (float)(r0 * rs), w1 = (float)(r1 * rs), w2 = (float)(r2 * rs);
    const float* p2 = points2 + b * kD2 * kS;
    float* op = interp + b * kD2 * kN + n;
    // per-d writes are coalesced across the 256 threads (consecutive n)
    for (int d = 0; d < kD2; ++d) {
        const float* row = p2 + d * kS;   // 8 KB row, L1-resident gathers
        op[d * kN] = w0 * row[i0] + w1 * row[i1] + w2 * row[i2];
    }
}

// ---------------- Fused GEMM (+optional BN-ReLU on load) + BN-stats --------
// fp32 baseline: 128(o) x 128(n) tile, 256 threads, 8x8 per thread, K-chunk 32.
// CONCAT: input = [interp(256); points1(128)].  BNRELU: apply per-channel
// scale/shift + relu while staging the K operand.
// Epilogue: raw Y store + per-channel sum/sumsq (shuffle-reduce + atomics).
template <int K, int MTOT, bool CONCAT, bool BNRELU>
__global__ __launch_bounds__(256) void gemm_bn_kernel(
    const float* __restrict__ W, const float* __restrict__ Xa,
    const float* __restrict__ Xb, const float* __restrict__ scale,
    const float* __restrict__ shift, float* __restrict__ Y,
    float* __restrict__ gsum, float* __restrict__ gsq)
{
    constexpr int TO = 128, TN = 128, TK = 32;
    __shared__ float Wt[TK][TO + 4];   // +4 pad: conflict-free b128 reads
    __shared__ float Xt[TK][TN];
    __shared__ float ssum[TO], ssq[TO];
    const int t = threadIdx.x;
    const int tx = t & 15, ty = t >> 4;
    const int bn = blockIdx.x * TN;
    const int bo = blockIdx.y * TO;
    const int b = blockIdx.z;

    float acc[8][8];
#pragma unroll
    for (int i = 0; i < 8; ++i)
#pragma unroll
        for (int j = 0; j < 8; ++j) acc[i][j] = 0.f;

    const int kk = t & 31, wo = t >> 5;    // W staging: coalesced in k
    const int xn = t & 127, xc = t >> 7;   // X staging: coalesced in n

    for (int k0 = 0; k0 < K; k0 += TK) {
#pragma unroll
        for (int p = 0; p < TO / 8; ++p) {
            int o = wo + p * 8;
            Wt[kk][o] = W[(bo + o) * K + k0 + kk];
        }
#pragma unroll
        for (int p = 0; p < TK / 2; ++p) {
            int c = k0 + xc + p * 2;
            float v;
            if constexpr (CONCAT) {
                v = (c < kD2) ? Xa[(b * kD2 + c) * kN + bn + xn]
                              : Xb[(b * kD1 + (c - kD2)) * kN + bn + xn];
            } else {
                v = Xa[(b * K + c) * kN + bn + xn];
                if constexpr (BNRELU) v = fmaxf(fmaf(v, scale[c], shift[c]), 0.f);
            }
            Xt[xc + p * 2][xn] = v;
        }
        __syncthreads();
#pragma unroll 8
        for (int k = 0; k < TK; ++k) {
            f32x4 A0 = *(const f32x4*)&Wt[k][ty * 8];
            f32x4 A1 = *(const f32x4*)&Wt[k][ty * 8 + 4];
            f32x4 B0 = *(const f32x4*)&Xt[k][tx * 8];
            f32x4 B1 = *(const f32x4*)&Xt[k][tx * 8 + 4];
            float a[8] = {A0[0], A0[1], A0[2], A0[3], A1[0], A1[1], A1[2], A1[3]};
            float bv[8] = {B0[0], B0[1], B0[2], B0[3], B1[0], B1[1], B1[2], B1[3]};
#pragma unroll
            for (int i = 0; i < 8; ++i)
#pragma unroll
                for (int j = 0; j < 8; ++j)
                    acc[i][j] = fmaf(a[i], bv[j], acc[i][j]);
        }
        __syncthreads();
    }

    // conv bias is skipped everywhere: BN's mean subtraction cancels it exactly.
    float* yb = Y + (b * MTOT + bo) * kN;
#pragma unroll
    for (int i = 0; i < 8; ++i) {
        const int ol = ty * 8 + i;
        float ps = 0.f, pq = 0.f;
#pragma unroll
        for (int j = 0; j < 8; ++j) { float v = acc[i][j]; ps += v; pq += v * v; }
#pragma unroll
        for (int off = 1; off < 16; off <<= 1) {   // reduce across the 16 tx lanes
            ps += __shfl_xor(ps, off);
            pq += __shfl_xor(pq, off);
        }
        if (tx == 0) { ssum[ol] = ps; ssq[ol] = pq; }
        f32x4 v0 = {acc[i][0], acc[i][1], acc[i][2], acc[i][3]};
        f32x4 v1 = {acc[i][4], acc[i][5], acc[i][6], acc[i][7]};
        f32x4* dst = (f32x4*)(yb + ol * kN + bn + tx * 8);
        dst[0] = v0; dst[1] = v1;
    }
    __syncthreads();
    if (t < TO) {
        atomicAdd(&gsum[bo + t], ssum[t]);
        atomicAdd(&gsq[bo + t], ssq[t]);
    }
}

// ---------------- BN stat finalize: scale/shift per channel ----------------
__global__ void bn_finalize_kernel(const float* __restrict__ gsum, const float* __restrict__ gsq,
                                   const float* __restrict__ g, const float* __restrict__ be,
                                   float* __restrict__ scale, float* __restrict__ shift, int M)
{
    int t = threadIdx.x;
    if (t < M) {
        const float invn = 1.0f / 65536.0f;   // B*N samples per channel
        float mean = gsum[t] * invn;
        float var = gsq[t] * invn - mean * mean;   // biased var (jnp.var default)
        float sc = g[t] * rsqrtf(var + kEps);
        scale[t] = sc;
        shift[t] = fmaf(-mean, sc, be[t]);
    }
}

// ---------------- Final in-place BN+ReLU on d_out --------------------------
__global__ __launch_bounds__(256) void bn_relu_out_kernel(
    float* __restrict__ out, const float* __restrict__ scale, const float* __restrict__ shift)
{
    const int total = kB * kM1 * kN / 4;
    for (int idx = blockIdx.x * blockDim.x + threadIdx.x; idx < total;
         idx += gridDim.x * blockDim.x) {
        const int p = (idx >> 11) & 127;   // channel = (idx*4 / 8192) % 128
        const float sc = scale[p], sh = shift[p];
        f32x4 v = ((f32x4*)out)[idx];
#pragma unroll
        for (int j = 0; j < 4; ++j) v[j] = fmaxf(fmaf(v[j], sc, sh), 0.f);
        ((f32x4*)out)[idx] = v;
    }
}

extern "C" void kernel_launch(void* const* d_in, const int* in_sizes, int n_in,
                              void* d_out, int out_size, void* d_ws, size_t ws_size,
                              hipStream_t stream)
{
    const float* xyz1    = (const float*)d_in[0];
    const float* xyz2    = (const float*)d_in[1];
    const float* points1 = (const float*)d_in[2];
    const float* points2 = (const float*)d_in[3];
    const float* w0      = (const float*)d_in[4];
    // d_in[5] = b0, d_in[9] = b1: conv biases cancel in BatchNorm -> unused
    const float* g0      = (const float*)d_in[6];
    const float* be0     = (const float*)d_in[7];
    const float* w1      = (const float*)d_in[8];
    const float* g1      = (const float*)d_in[10];
    const float* be1     = (const float*)d_in[11];
    float* out = (float*)d_out;

    char* ws = (char*)d_ws;
    float* interp = (float*)ws;                                   // 64 MiB
    float* y0     = (float*)(ws + (size_t)64 * 1024 * 1024);      // 64 MiB
    float* stats  = (float*)(ws + (size_t)128 * 1024 * 1024);     // ~6 KB
    float* sum0 = stats,         *sq0 = stats + 256;
    float* sum1 = stats + 512,   *sq1 = stats + 640;
    float* scale0 = stats + 768, *shift0 = stats + 1024;
    float* scale1 = stats + 1280, *shift1 = stats + 1408;

    hipMemsetAsync(stats, 0, 768 * sizeof(float), stream);
    knn_interp_kernel<<<256, 256, 0, stream>>>(xyz1, xyz2, points2, interp);
    gemm_bn_kernel<kCin, kM0, true, false><<<dim3(64, 2, 8), 256, 0, stream>>>(
        w0, interp, points1, nullptr, nullptr, y0, sum0, sq0);
    bn_finalize_kernel<<<1, 256, 0, stream>>>(sum0, sq0, g0, be0, scale0, shift0, 256);
    gemm_bn_kernel<kM0, kM1, false, true><<<dim3(64, 1, 8), 256, 0, stream>>>(
        w1, y0, nullptr, scale0, shift0, out, sum1, sq1);
    bn_finalize_kernel<<<1, 128, 0, stream>>>(sum1, sq1, g1, be1, scale1, shift1, 128);
    bn_relu_out_kernel<<<4096, 256, 0, stream>>>(out, scale1, shift1);
}

// Round 3
// 182.882 us; speedup vs baseline: 2.9392x; 2.9392x over previous
//
#include <hip/hip_runtime.h>
#include <hip/hip_bf16.h>

constexpr int kB = 8, kN = 8192, kS = 2048;
constexpr int kD1 = 128, kD2 = 256, kCin = 384, kM0 = 256, kM1 = 128;
constexpr float kEps = 1e-5f;

typedef float f32x4 __attribute__((ext_vector_type(4)));
typedef short bf16x8 __attribute__((ext_vector_type(8)));
typedef unsigned short u16x4 __attribute__((ext_vector_type(4)));

__device__ inline unsigned short f2bf(float f) {
    __hip_bfloat16 h = __float2bfloat16(f);
    return *reinterpret_cast<unsigned short*>(&h);
}
__device__ inline float bf2f(unsigned short u) {
    unsigned int v = (unsigned int)u << 16;
    return *reinterpret_cast<float*>(&v);
}

// ---------------- Transpose points2 [b][c][s] -> p2t [b][s][c] (f32) -------
__global__ __launch_bounds__(256) void transpose_p2_kernel(
    const float* __restrict__ in, float* __restrict__ out)
{
    __shared__ float tl[64][69];   // pad 69: 2-way-max bank aliasing on column reads
    const int s0 = blockIdx.x * 64, c0 = blockIdx.y * 64, b = blockIdx.z;
    const int t = threadIdx.x;
    const int rlo = t >> 4, rhi = t & 15;
#pragma unroll
    for (int r = 0; r < 4; ++r) {
        const int cl = rlo + r * 16;
        f32x4 v = *(const f32x4*)(in + ((size_t)(b * kD2 + c0 + cl)) * kS + s0 + rhi * 4);
#pragma unroll
        for (int j = 0; j < 4; ++j) tl[cl][rhi * 4 + j] = v[j];
    }
    __syncthreads();
#pragma unroll
    for (int r = 0; r < 4; ++r) {
        const int sl = rlo + r * 16;
        f32x4 v;
#pragma unroll
        for (int j = 0; j < 4; ++j) v[j] = tl[rhi * 4 + j][sl];
        *(f32x4*)(out + ((size_t)(b * kS + s0 + sl)) * kD2 + c0 + rhi * 4) = v;
    }
}

// ------------- Transpose points1 [b][c][n] -> xt[b][n][256+c] (bf16) -------
__global__ __launch_bounds__(256) void transpose_p1_kernel(
    const float* __restrict__ in, unsigned short* __restrict__ xt)
{
    __shared__ float tl[64][69];
    const int n0 = blockIdx.x * 64, c0 = blockIdx.y * 64, b = blockIdx.z;
    const int t = threadIdx.x;
    const int rlo = t >> 4, rhi = t & 15;
#pragma unroll
    for (int r = 0; r < 4; ++r) {
        const int cl = rlo + r * 16;
        f32x4 v = *(const f32x4*)(in + ((size_t)(b * kD1 + c0 + cl)) * kN + n0 + rhi * 4);
#pragma unroll
        for (int j = 0; j < 4; ++j) tl[cl][rhi * 4 + j] = v[j];
    }
    __syncthreads();
#pragma unroll
    for (int r = 0; r < 4; ++r) {
        const int nl = rlo + r * 16;
        u16x4 u;
#pragma unroll
        for (int j = 0; j < 4; ++j) u[j] = f2bf(tl[rhi * 4 + j][nl]);
        *(u16x4*)(xt + ((size_t)(b * kN + n0 + nl)) * kCin + 256 + c0 + rhi * 4) = u;
    }
}

// ---------------- 3-NN + interp: 4 threads per query ------------------------
// pass1 (fp32, no indices): per-thread top-3 of reduced dist d'=|s|^2-2p.s over
// its 512 sources (s = 4i+c), branchless min/med3 chains; shfl-merge sorted
// triples across the quad -> global 3rd-smallest m2; cutoff = m2+1e-3
// (fp32 d' err ~1e-6, margin ~800x).
// pass2: rescan; candidates take exact fp64 (p-s)^2 insert with index; quad
// shfl-merge with (d, idx) lexicographic order (ties -> lower index, matching
// stable lax.top_k).  Gather: p2t rows are contiguous; quad-cooperative f32x4
// reads, weighted sum, bf16 row write into xt[b][n][0:256].
__global__ __launch_bounds__(256) void knn_interp_kernel(
    const float* __restrict__ xyz1, const float* __restrict__ xyz2,
    const float* __restrict__ p2t, unsigned short* __restrict__ xt)
{
    __shared__ f32x4 sp[kS];                 // (sx,sy,sz,|s|^2) 32 KB
    const int b = blockIdx.x >> 7;
    const int n0 = (blockIdx.x & 127) << 6;  // 64 queries per block
    const int t = threadIdx.x;
    const float* x2 = xyz2 + b * 3 * kS;
    for (int s = t; s < kS; s += 256) {
        float sx = x2[s], sy = x2[kS + s], sz = x2[2 * kS + s];
        f32x4 q = {sx, sy, sz, fmaf(sx, sx, fmaf(sy, sy, sz * sz))};
        sp[s] = q;
    }
    __syncthreads();
    const int q = t >> 2, c = t & 3;
    const int n = n0 + q;
    const float* x1 = xyz1 + b * 3 * kN;
    const float px = x1[n], py = x1[kN + n], pz = x1[2 * kN + n];
    const float ax = -2.f * px, ay = -2.f * py, az = -2.f * pz;

    // pass 1: two chains over this thread's sources
    float a0 = 1e30f, a1 = 1e30f, a2 = 1e30f;
    float c0v = 1e30f, c1v = 1e30f, c2v = 1e30f;
    for (int i = 0; i < 512; i += 2) {
        f32x4 qa = sp[4 * i + c];
        f32x4 qb = sp[4 * i + 4 + c];
        float e0 = fmaf(ax, qa[0], fmaf(ay, qa[1], fmaf(az, qa[2], qa[3])));
        float e1 = fmaf(ax, qb[0], fmaf(ay, qb[1], fmaf(az, qb[2], qb[3])));
        float t1 = __builtin_amdgcn_fmed3f(e0, a0, a1);
        float t2 = __builtin_amdgcn_fmed3f(e0, a1, a2);
        a0 = fminf(a0, e0); a1 = t1; a2 = t2;
        t1 = __builtin_amdgcn_fmed3f(e1, c0v, c1v);
        t2 = __builtin_amdgcn_fmed3f(e1, c1v, c2v);
        c0v = fminf(c0v, e1); c1v = t1; c2v = t2;
    }
    // merge the two sorted triples, then across the quad (shfl_xor 1,2)
    float x0 = fminf(a0, c0v);
    float x1v = fminf(fmaxf(a0, c0v), fminf(a1, c1v));
    float x2v = fminf(fminf(fmaxf(a1, c0v), fmaxf(a0, c1v)), fminf(a2, c2v));
#pragma unroll
    for (int off = 1; off <= 2; off <<= 1) {
        float y0 = __shfl_xor(x0, off), y1 = __shfl_xor(x1v, off), y2 = __shfl_xor(x2v, off);
        float z0 = fminf(x0, y0);
        float z1 = fminf(fmaxf(x0, y0), fminf(x1v, y1));
        float z2 = fminf(fminf(fmaxf(x1v, y0), fmaxf(x0, y1)), fminf(x2v, y2));
        x0 = z0; x1v = z1; x2v = z2;
    }
    const float cutoff = x2v + 1e-3f;

    // pass 2: exact fp64 top-3 with indices among filtered candidates
    double d0 = 1e300, d1 = 1e300, d2 = 1e300;
    int i0 = 0, i1 = 0, i2 = 0;
    const double dpx = (double)px, dpy = (double)py, dpz = (double)pz;
    for (int i = 0; i < 512; ++i) {
        const int s = 4 * i + c;
        f32x4 qv = sp[s];
        float df = fmaf(ax, qv[0], fmaf(ay, qv[1], fmaf(az, qv[2], qv[3])));
        if (df <= cutoff) {
            double ex = dpx - (double)qv[0], ey = dpy - (double)qv[1], ez = dpz - (double)qv[2];
            double d = ex * ex + ey * ey + ez * ez;
            if (d < d2) {
                if (d < d1) {
                    if (d < d0) { d2 = d1; i2 = i1; d1 = d0; i1 = i0; d0 = d; i0 = s; }
                    else        { d2 = d1; i2 = i1; d1 = d;  i1 = s; }
                } else          { d2 = d;  i2 = s; }
            }
        }
    }
    // quad merge with lexicographic (d, idx) order
#pragma unroll
    for (int off = 1; off <= 2; off <<= 1) {
        double pd0 = __shfl_xor(d0, off), pd1 = __shfl_xor(d1, off), pd2 = __shfl_xor(d2, off);
        int pi0 = __shfl_xor(i0, off), pi1 = __shfl_xor(i1, off), pi2 = __shfl_xor(i2, off);
#pragma unroll
        for (int m = 0; m < 3; ++m) {
            double pd = (m == 0) ? pd0 : (m == 1) ? pd1 : pd2;
            int pi = (m == 0) ? pi0 : (m == 1) ? pi1 : pi2;
            if (pd < d2 || (pd == d2 && pi < i2)) {
                if (pd < d1 || (pd == d1 && pi < i1)) {
                    if (pd < d0 || (pd == d0 && pi < i0)) {
                        d2 = d1; i2 = i1; d1 = d0; i1 = i0; d0 = pd; i0 = pi;
                    } else { d2 = d1; i2 = i1; d1 = pd; i1 = pi; }
                } else { d2 = pd; i2 = pi; }
            }
        }
    }
    const double r0 = 1.0 / (d0 + 1e-8), r1 = 1.0 / (d1 + 1e-8), r2 = 1.0 / (d2 + 1e-8);
    const double rs = 1.0 / (r0 + r1 + r2);
    const float w0 = (float)(r0 * rs), w1 = (float)(r1 * rs), w2 = (float)(r2 * rs);

    // gather: 3 contiguous 1 KB rows of p2t, quad-cooperative
    const f32x4* row0 = (const f32x4*)(p2t + ((size_t)(b * kS) + i0) * kD2);
    const f32x4* row1 = (const f32x4*)(p2t + ((size_t)(b * kS) + i1) * kD2);
    const f32x4* row2 = (const f32x4*)(p2t + ((size_t)(b * kS) + i2) * kD2);
    unsigned short* dst = xt + ((size_t)(b * kN) + n) * kCin;
#pragma unroll 4
    for (int j = 0; j < 16; ++j) {
        const int ch = c + 4 * j;                   // f32x4 chunk index (0..63)
        f32x4 v = w0 * row0[ch] + w1 * row1[ch] + w2 * row2[ch];
        u16x4 u = {f2bf(v[0]), f2bf(v[1]), f2bf(v[2]), f2bf(v[3])};
        *(u16x4*)(dst + ch * 4) = u;
    }
}

// ---------------- bf16 MFMA GEMM + BN-stats --------------------------------
// X rows [n][K] bf16 (xt or y0t). W [MTOT][K] f32 -> bf16 on stage.
// 128x128 tile, 4 waves (2m x 2n), 16x16x32 MFMA, K-step 32, XOR-swizzled LDS.
// BNRELU: apply layer-0 scale/shift + relu while staging X.
// OUTBF16: write y0t[b][n][m] bf16 (layer0) else raw f32 [b][m][n] (layer1).
__device__ inline int swz(int row, int ks) {   // ushort index of a 16B slot
    return row * 32 + ((ks ^ ((row >> 1) & 3)) << 3);
}

template <int K, int MTOT, bool BNRELU, bool OUTBF16>
__global__ __launch_bounds__(256) void gemm_bn_kernel(
    const float* __restrict__ W, const unsigned short* __restrict__ X,
    const float* __restrict__ scale, const float* __restrict__ shift,
    unsigned short* __restrict__ Yb, float* __restrict__ Yf,
    float* __restrict__ gsum, float* __restrict__ gsq)
{
    constexpr int BM = 128, BN = 128;
    __shared__ unsigned short Al[BM * 32], Bl[BN * 32];   // 8 KB each, swizzled
    __shared__ float ssum[BM], ssq[BM];
    __shared__ float s_sc[256], s_sh[256];
    const int t = threadIdx.x;
    const int bn = blockIdx.x * BN, bo = blockIdx.y * BM, b = blockIdx.z;
    const int l = t & 63, w = t >> 6;
    const int wm = (w >> 1) * 64, wn = (w & 1) * 64;
    const int lrow = l & 15, lks = l >> 4;

    if constexpr (BNRELU) {
        if (t < K) { s_sc[t] = scale[t]; s_sh[t] = shift[t]; }
    }
    if (t < BM) { ssum[t] = 0.f; ssq[t] = 0.f; }
    __syncthreads();

    f32x4 acc[4][4] = {};
    for (int k0 = 0; k0 < K; k0 += 32) {
        // stage A: W f32 -> bf16
#pragma unroll
        for (int r = 0; r < 2; ++r) {
            const int sid = t + r * 256;
            const int m = sid >> 2, ks = sid & 3;
            const float* wp = W + (size_t)(bo + m) * K + k0 + ks * 8;
            f32x4 wa = *(const f32x4*)wp, wb = *(const f32x4*)(wp + 4);
            bf16x8 u;
#pragma unroll
            for (int j = 0; j < 4; ++j) { u[j] = (short)f2bf(wa[j]); u[j + 4] = (short)f2bf(wb[j]); }
            *(bf16x8*)(Al + swz(m, ks)) = u;
        }
        // stage B: X bf16 rows (+ optional BN/ReLU in f32)
#pragma unroll
        for (int r = 0; r < 2; ++r) {
            const int sid = t + r * 256;
            const int nl = sid >> 2, ks = sid & 3;
            bf16x8 v = *(const bf16x8*)(X + ((size_t)(b * kN) + bn + nl) * K + k0 + ks * 8);
            if constexpr (BNRELU) {
#pragma unroll
                for (int j = 0; j < 8; ++j) {
                    const int ch = k0 + ks * 8 + j;
                    float f = fmaxf(fmaf(bf2f((unsigned short)v[j]), s_sc[ch], s_sh[ch]), 0.f);
                    v[j] = (short)f2bf(f);
                }
            }
            *(bf16x8*)(Bl + swz(nl, ks)) = v;
        }
        __syncthreads();
        bf16x8 af[4], bfr[4];
#pragma unroll
        for (int f = 0; f < 4; ++f) af[f]  = *(const bf16x8*)(Al + swz(wm + f * 16 + lrow, lks));
#pragma unroll
        for (int f = 0; f < 4; ++f) bfr[f] = *(const bf16x8*)(Bl + swz(wn + f * 16 + lrow, lks));
#pragma unroll
        for (int mi = 0; mi < 4; ++mi)
#pragma unroll
            for (int ni = 0; ni < 4; ++ni)
                acc[mi][ni] = __builtin_amdgcn_mfma_f32_16x16x32_bf16(af[mi], bfr[ni], acc[mi][ni], 0, 0, 0);
        __syncthreads();
    }

    // BN statistics: sum / sumsq per output channel over this block's 128 n
#pragma unroll
    for (int mi = 0; mi < 4; ++mi) {
#pragma unroll
        for (int r = 0; r < 4; ++r) {
            float ps = 0.f, pq = 0.f;
#pragma unroll
            for (int ni = 0; ni < 4; ++ni) { float v = acc[mi][ni][r]; ps += v; pq += v * v; }
#pragma unroll
            for (int off = 1; off < 16; off <<= 1) { ps += __shfl_xor(ps, off); pq += __shfl_xor(pq, off); }
            if (lrow == 0) {
                const int m = wm + mi * 16 + lks * 4 + r;
                atomicAdd(&ssum[m], ps); atomicAdd(&ssq[m], pq);
            }
        }
    }

    // output
    if constexpr (OUTBF16) {
#pragma unroll
        for (int mi = 0; mi < 4; ++mi)
#pragma unroll
            for (int ni = 0; ni < 4; ++ni) {
                const int m = bo + wm + mi * 16 + lks * 4;
                const int n = bn + wn + ni * 16 + lrow;
                u16x4 u = {f2bf(acc[mi][ni][0]), f2bf(acc[mi][ni][1]),
                           f2bf(acc[mi][ni][2]), f2bf(acc[mi][ni][3])};
                *(u16x4*)(Yb + ((size_t)(b * kN) + n) * MTOT + m) = u;
            }
    } else {
#pragma unroll
        for (int mi = 0; mi < 4; ++mi)
#pragma unroll
            for (int ni = 0; ni < 4; ++ni) {
                const int n = bn + wn + ni * 16 + lrow;
#pragma unroll
                for (int r = 0; r < 4; ++r) {
                    const int m = bo + wm + mi * 16 + lks * 4 + r;
                    Yf[((size_t)(b * MTOT) + m) * kN + n] = acc[mi][ni][r];
                }
            }
    }
    __syncthreads();
    if (t < BM) {
        atomicAdd(&gsum[bo + t], ssum[t]);
        atomicAdd(&gsq[bo + t], ssq[t]);
    }
}

// ---------------- BN stat finalize -----------------------------------------
__global__ void bn_finalize_kernel(const float* __restrict__ gsum, const float* __restrict__ gsq,
                                   const float* __restrict__ g, const float* __restrict__ be,
                                   float* __restrict__ scale, float* __restrict__ shift, int M)
{
    int t = threadIdx.x;
    if (t < M) {
        const float invn = 1.0f / 65536.0f;
        float mean = gsum[t] * invn;
        float var = gsq[t] * invn - mean * mean;   // biased var
        float sc = g[t] * rsqrtf(var + kEps);
        scale[t] = sc;
        shift[t] = fmaf(-mean, sc, be[t]);
    }
}

// ---------------- Final in-place BN+ReLU on d_out --------------------------
__global__ __launch_bounds__(256) void bn_relu_out_kernel(
    float* __restrict__ out, const float* __restrict__ scale, const float* __restrict__ shift)
{
    const int total = kB * kM1 * kN / 4;
    for (int idx = blockIdx.x * blockDim.x + threadIdx.x; idx < total;
         idx += gridDim.x * blockDim.x) {
        const int p = (idx >> 11) & 127;
        const float sc = scale[p], sh = shift[p];
        f32x4 v = ((f32x4*)out)[idx];
#pragma unroll
        for (int j = 0; j < 4; ++j) v[j] = fmaxf(fmaf(v[j], sc, sh), 0.f);
        ((f32x4*)out)[idx] = v;
    }
}

extern "C" void kernel_launch(void* const* d_in, const int* in_sizes, int n_in,
                              void* d_out, int out_size, void* d_ws, size_t ws_size,
                              hipStream_t stream)
{
    const float* xyz1    = (const float*)d_in[0];
    const float* xyz2    = (const float*)d_in[1];
    const float* points1 = (const float*)d_in[2];
    const float* points2 = (const float*)d_in[3];
    const float* w0      = (const float*)d_in[4];
    // d_in[5] = b0, d_in[9] = b1: conv biases cancel in BatchNorm -> unused
    const float* g0      = (const float*)d_in[6];
    const float* be0     = (const float*)d_in[7];
    const float* w1      = (const float*)d_in[8];
    const float* g1      = (const float*)d_in[10];
    const float* be1     = (const float*)d_in[11];
    float* out = (float*)d_out;

    char* ws = (char*)d_ws;
    unsigned short* xt  = (unsigned short*)ws;                           // 48 MiB  [B][N][384] bf16
    float* p2t          = (float*)(ws + (size_t)50331648);               // 16 MiB  [B][S][256] f32
    unsigned short* y0t = (unsigned short*)(ws + (size_t)67108864);      // 32 MiB  [B][N][256] bf16
    float* stats        = (float*)(ws + (size_t)100663296);
    float* sum0 = stats,          *sq0 = stats + 256;
    float* sum1 = stats + 512,    *sq1 = stats + 640;
    float* scale0 = stats + 768,  *shift0 = stats + 1024;
    float* scale1 = stats + 1280, *shift1 = stats + 1408;

    hipMemsetAsync(stats, 0, 768 * sizeof(float), stream);
    transpose_p2_kernel<<<dim3(32, 4, 8), 256, 0, stream>>>(points2, p2t);
    transpose_p1_kernel<<<dim3(128, 2, 8), 256, 0, stream>>>(points1, xt);
    knn_interp_kernel<<<1024, 256, 0, stream>>>(xyz1, xyz2, p2t, xt);
    gemm_bn_kernel<kCin, kM0, false, true><<<dim3(64, 2, 8), 256, 0, stream>>>(
        w0, xt, nullptr, nullptr, y0t, nullptr, sum0, sq0);
    bn_finalize_kernel<<<1, 256, 0, stream>>>(sum0, sq0, g0, be0, scale0, shift0, 256);
    gemm_bn_kernel<kM0, kM1, true, false><<<dim3(64, 1, 8), 256, 0, stream>>>(
        w1, y0t, scale0, shift0, nullptr, out, sum1, sq1);
    bn_finalize_kernel<<<1, 128, 0, stream>>>(sum1, sq1, g1, be1, scale1, shift1, 128);
    bn_relu_out_kernel<<<2048, 256, 0, stream>>>(out, scale1, shift1);
}